// Round 3
// baseline (12820.694 us; speedup 1.0000x reference)
//
#include <hip/hip_runtime.h>

#define NN 200000
#define NB 64
#define NWG (NN / NB)   // 3125

typedef unsigned short u16;
typedef unsigned int u32;
typedef __attribute__((ext_vector_type(8))) short short8;
typedef __attribute__((ext_vector_type(4))) float f32x4;

__device__ __forceinline__ u16 f2bf(float x) {
  u32 u = __float_as_uint(x);
  u += 0x7FFFu + ((u >> 16) & 1u);
  return (u16)(u >> 16);
}
__device__ __forceinline__ float sigf(float x) {
  float e = __builtin_amdgcn_exp2f(x * -1.44269504f);
  return __builtin_amdgcn_rcpf(1.0f + e);
}
__device__ __forceinline__ float tanhf_(float x) {
  float e = __builtin_amdgcn_exp2f(x * 2.88539008f);
  return 1.0f - 2.0f * __builtin_amdgcn_rcpf(1.0f + e);
}

// msg[n][k] = bf16(feat[n][k] / out_norm[n]); 16 threads per row, 8 elems each
__global__ void k_prep_msg(const float* __restrict__ feat, const float* __restrict__ onorm,
                           u16* __restrict__ msg) {
  int i = blockIdx.x * 256 + threadIdx.x;   // 3,200,000 total, exact
  int row = i >> 4, c8 = (i & 15) * 8;
  const float4 a = *(const float4*)(feat + (size_t)row * 128 + c8);
  const float4 b = *(const float4*)(feat + (size_t)row * 128 + c8 + 4);
  float s = 1.0f / onorm[row];
  short8 v = { (short)f2bf(a.x * s), (short)f2bf(a.y * s), (short)f2bf(a.z * s), (short)f2bf(a.w * s),
               (short)f2bf(b.x * s), (short)f2bf(b.y * s), (short)f2bf(b.z * s), (short)f2bf(b.w * s) };
  *(short8*)(msg + (size_t)row * 128 + c8) = v;
}

__global__ void k_prep_w(const float* __restrict__ Wih, const float* __restrict__ Whh,
                         const float* __restrict__ Wlin, const float* __restrict__ bih,
                         const float* __restrict__ bhh, u16* __restrict__ wihb,
                         u16* __restrict__ whhb, u16* __restrict__ wlinb,
                         float* __restrict__ bsum) {
  int i = blockIdx.x * 256 + threadIdx.x;   // 147,968 total, exact
  if (i < 65536) wihb[i] = f2bf(Wih[i]);
  else if (i < 131072) whhb[i - 65536] = f2bf(Whh[i - 65536]);
  else if (i < 147456) wlinb[i - 131072] = f2bf(Wlin[i - 131072]);
  else { int j = i - 147456; bsum[j] = bih[j] + bhh[j]; }
}

__global__ void k_hist(const int* __restrict__ degs, int* __restrict__ hist, int n) {
  __shared__ int lh[33];
  if (threadIdx.x < 33) lh[threadIdx.x] = 0;
  __syncthreads();
  int i = blockIdx.x * 256 + threadIdx.x;
  if (i < n) atomicAdd(&lh[degs[i]], 1);
  __syncthreads();
  if (threadIdx.x < 33 && lh[threadIdx.x]) atomicAdd(&hist[threadIdx.x], lh[threadIdx.x]);
}

// descending-degree exclusive prefix (longest blocks scheduled first)
__global__ void k_scan(const int* __restrict__ hist, int* __restrict__ basep) {
  if (threadIdx.x == 0 && blockIdx.x == 0) {
    int a = 0;
    for (int d = 32; d >= 1; --d) { basep[d] = a; a += hist[d]; }
    basep[0] = a;
  }
}

// block-aggregated scatter: one global atomic per (block, degree) instead of per node
__global__ void k_scatter(const int* __restrict__ degs, int* __restrict__ basep,
                          int* __restrict__ perm, int n) {
  __shared__ int lh[33], lbase[33], lc[33];
  int t = threadIdx.x;
  if (t < 33) { lh[t] = 0; lc[t] = 0; }
  __syncthreads();
  int i = blockIdx.x * 256 + t;
  int d = (i < n) ? degs[i] : 0;
  if (i < n) atomicAdd(&lh[d], 1);
  __syncthreads();
  if (t < 33 && lh[t]) lbase[t] = atomicAdd(&basep[t], lh[t]);
  __syncthreads();
  if (i < n) { int r = atomicAdd(&lc[d], 1); perm[lbase[d] + r] = i; }
}

__global__ __launch_bounds__(512, 8) void k_main(
    const u16* __restrict__ msg, const u16* __restrict__ wihb,
    const u16* __restrict__ whhb, const u16* __restrict__ wlinb,
    const float* __restrict__ bsum, const float* __restrict__ blin,
    const float* __restrict__ inorm, const int* __restrict__ nbrs,
    const int* __restrict__ degs, const int* __restrict__ perm,
    float* __restrict__ out) {
  __shared__ alignas(16) u16 Xl[64 * 136];   // 17408 B
  __shared__ alignas(16) u16 Hl[64 * 136];   // 17408 B
  __shared__ int gidl[64];
  // total ~35.3 KB -> 4 blocks/CU

  const int tid = threadIdx.x;
  const int w = tid >> 6;
  const int lane = tid & 63;
  const int l15 = lane & 15;
  const int g4 = lane >> 4;
  const int w16 = w * 16;
  const int gr = tid >> 4;         // gather rows gr and gr+32
  const int gc = (tid & 15) * 8;
  const int base = blockIdx.x * NB;

  if (tid < NB) gidl[tid] = perm[base + tid];
  // zero Hl (64*136 u16 = 4352 u32)
  {
    u32* hz = (u32*)Hl;
#pragma unroll
    for (int s = 0; s < 8; ++s) hz[tid + s * 512] = 0;
    if (tid < 256) hz[tid + 4096] = 0;
  }
  __syncthreads();

  const int gid0 = gidl[gr], gid1 = gidl[gr + 32];

  // per-wave B fragments (row-major W rows are exactly the B-frag layout)
  short8 fih[4][4], fhh[4][4];
#pragma unroll
  for (int g = 0; g < 4; ++g)
#pragma unroll
    for (int kk = 0; kk < 4; ++kk) {
      size_t o = (size_t)(g * 128 + w16 + l15) * 128 + kk * 32 + g4 * 8;
      fih[g][kk] = *(const short8*)(wihb + o);
      fhh[g][kk] = *(const short8*)(whhb + o);
    }
  float bias[4];
#pragma unroll
  for (int g = 0; g < 4; ++g) bias[g] = bsum[g * 128 + w16 + l15];

  // packed per-cell degrees (u8 x4 per row-frag)
  u32 dgp[4];
#pragma unroll
  for (int r = 0; r < 4; ++r) {
    u32 p = 0;
#pragma unroll
    for (int q = 0; q < 4; ++q) p |= ((u32)degs[gidl[r * 16 + g4 * 4 + q]]) << (8 * q);
    dgp[r] = p;
  }
  const int maxdeg = degs[gidl[0]];   // sorted descending -> first is WG max

  // prologue of the 2-deep prefetch pipeline:
  //   nbrn holds neighbor index for step t+1; pf holds msg data for step t
  int nbrn0 = nbrs[(size_t)gid0 * 32];
  int nbrn1 = nbrs[(size_t)gid1 * 32];
  short8 pf0 = *(const short8*)(msg + (size_t)nbrn0 * 128 + gc);
  short8 pf1 = *(const short8*)(msg + (size_t)nbrn1 * 128 + gc);
  if (maxdeg > 1) {
    nbrn0 = nbrs[(size_t)gid0 * 32 + 1];
    nbrn1 = nbrs[(size_t)gid1 * 32 + 1];
  }

  float c[4][4] = {};
  u16 hbf[4][4] = {};

  for (int t = 0; t < maxdeg; ++t) {
    // commit X(t) and h(t-1)
    *(short8*)(&Xl[gr * 136 + gc]) = pf0;
    *(short8*)(&Xl[(gr + 32) * 136 + gc]) = pf1;
    if (t > 0) {
#pragma unroll
      for (int rr = 0; rr < 4; ++rr)
#pragma unroll
        for (int q = 0; q < 4; ++q)
          Hl[(rr * 16 + g4 * 4 + q) * 136 + w16 + l15] = hbf[rr][q];
    }
    __syncthreads();   // barrier A: tiles ready

    if (t + 1 < maxdeg) {   // gather msg(t+1) with index loaded last step
      pf0 = *(const short8*)(msg + (size_t)nbrn0 * 128 + gc);
      pf1 = *(const short8*)(msg + (size_t)nbrn1 * 128 + gc);
    }
    if (t + 2 < maxdeg) {   // load neighbor index for step t+2
      nbrn0 = nbrs[(size_t)gid0 * 32 + t + 2];
      nbrn1 = nbrs[(size_t)gid1 * 32 + t + 2];
    }

    // two passes over row-fragments: acc stays at 32 regs; pass0's TRANS
    // epilogue overlaps pass1's MFMAs
#pragma unroll
    for (int rp = 0; rp < 2; ++rp) {
      f32x4 acc[2][4];
#pragma unroll
      for (int r = 0; r < 2; ++r)
#pragma unroll
        for (int g = 0; g < 4; ++g) acc[r][g] = (f32x4){bias[g], bias[g], bias[g], bias[g]};
#pragma unroll
      for (int kk = 0; kk < 4; ++kk) {
        short8 ax0 = *(const short8*)(&Xl[(rp * 32 + l15) * 136 + kk * 32 + g4 * 8]);
        short8 ax1 = *(const short8*)(&Xl[(rp * 32 + 16 + l15) * 136 + kk * 32 + g4 * 8]);
        short8 ah0 = *(const short8*)(&Hl[(rp * 32 + l15) * 136 + kk * 32 + g4 * 8]);
        short8 ah1 = *(const short8*)(&Hl[(rp * 32 + 16 + l15) * 136 + kk * 32 + g4 * 8]);
#pragma unroll
        for (int g = 0; g < 4; ++g) {
          acc[0][g] = __builtin_amdgcn_mfma_f32_16x16x32_bf16(ax0, fih[g][kk], acc[0][g], 0, 0, 0);
          acc[0][g] = __builtin_amdgcn_mfma_f32_16x16x32_bf16(ah0, fhh[g][kk], acc[0][g], 0, 0, 0);
          acc[1][g] = __builtin_amdgcn_mfma_f32_16x16x32_bf16(ax1, fih[g][kk], acc[1][g], 0, 0, 0);
          acc[1][g] = __builtin_amdgcn_mfma_f32_16x16x32_bf16(ah1, fhh[g][kk], acc[1][g], 0, 0, 0);
        }
      }
      // epilogue: LSTM cell (fp32 state, masked by t < deg)
#pragma unroll
      for (int r = 0; r < 2; ++r) {
        const int rr = rp * 2 + r;
#pragma unroll
        for (int q = 0; q < 4; ++q) {
          float iv = sigf(acc[r][0][q]);
          float fv = sigf(acc[r][1][q]);
          float gv = tanhf_(acc[r][2][q]);
          float ov = sigf(acc[r][3][q]);
          float cn = fv * c[rr][q] + iv * gv;
          float hn = ov * tanhf_(cn);
          bool act = (int)((dgp[rr] >> (8 * q)) & 255u) > t;
          c[rr][q] = act ? cn : c[rr][q];
          hbf[rr][q] = act ? f2bf(hn) : hbf[rr][q];
        }
      }
    }
    __syncthreads();   // barrier B: all reads done before next commit
  }

  // final h commit
#pragma unroll
  for (int rr = 0; rr < 4; ++rr)
#pragma unroll
    for (int q = 0; q < 4; ++q)
      Hl[(rr * 16 + g4 * 4 + q) * 136 + w16 + l15] = hbf[rr][q];
  __syncthreads();

  // out = (h @ W_lin^T) / in_norm + b_lin   (wave w owns out cols 16w..16w+15)
  short8 wl[4];
#pragma unroll
  for (int kk = 0; kk < 4; ++kk)
    wl[kk] = *(const short8*)(wlinb + (size_t)(w16 + l15) * 128 + kk * 32 + g4 * 8);
  f32x4 a2[4] = {};
#pragma unroll
  for (int kk = 0; kk < 4; ++kk)
#pragma unroll
    for (int r = 0; r < 4; ++r) {
      short8 ah = *(const short8*)(&Hl[(r * 16 + l15) * 136 + kk * 32 + g4 * 8]);
      a2[r] = __builtin_amdgcn_mfma_f32_16x16x32_bf16(ah, wl[kk], a2[r], 0, 0, 0);
    }
  float blv = blin[w16 + l15];
#pragma unroll
  for (int r = 0; r < 4; ++r)
#pragma unroll
    for (int q = 0; q < 4; ++q) {
      int nl = r * 16 + g4 * 4 + q;
      int g = gidl[nl];
      out[(size_t)g * 128 + w16 + l15] = a2[r][q] / inorm[g] + blv;
    }
}

extern "C" void kernel_launch(void* const* d_in, const int* in_sizes, int n_in,
                              void* d_out, int out_size, void* d_ws, size_t ws_size,
                              hipStream_t stream) {
  const float* feat    = (const float*)d_in[0];
  const float* in_norm = (const float*)d_in[1];
  const float* out_nrm = (const float*)d_in[2];
  const float* W_ih    = (const float*)d_in[3];
  const float* W_hh    = (const float*)d_in[4];
  const float* b_ih    = (const float*)d_in[5];
  const float* b_hh    = (const float*)d_in[6];
  const float* W_lin   = (const float*)d_in[7];
  const float* b_lin   = (const float*)d_in[8];
  const int* neighbors = (const int*)d_in[9];
  const int* degrees   = (const int*)d_in[10];
  float* out = (float*)d_out;

  char* ws = (char*)d_ws;
  u16* msg    = (u16*)(ws);                 // 51,200,000 B
  u16* wihb   = (u16*)(ws + 51200000);      //    131,072 B
  u16* whhb   = (u16*)(ws + 51331072);      //    131,072 B
  u16* wlinb  = (u16*)(ws + 51462144);      //     32,768 B
  float* bsum = (float*)(ws + 51494912);    //      2,048 B
  int* perm   = (int*)(ws + 51496960);      //    800,000 B
  int* hist   = (int*)(ws + 52296960);      // 64 ints
  int* basep  = hist + 64;                  // 33 ints
  if (ws_size < 52297600) return;           // need ~52.3 MB scratch

  hipMemsetAsync(hist, 0, 64 * 4, stream);
  k_prep_msg<<<12500, 256, 0, stream>>>(feat, out_nrm, msg);
  k_prep_w<<<578, 256, 0, stream>>>(W_ih, W_hh, W_lin, b_ih, b_hh, wihb, whhb, wlinb, bsum);
  k_hist<<<782, 256, 0, stream>>>(degrees, hist, NN);
  k_scan<<<1, 1, 0, stream>>>(hist, basep);
  k_scatter<<<782, 256, 0, stream>>>(degrees, basep, perm, NN);
  k_main<<<NWG, 512, 0, stream>>>(msg, wihb, whhb, wlinb, bsum, b_lin, in_norm,
                                  neighbors, degrees, perm, out);
}

// Round 4
// 5293.388 us; speedup vs baseline: 2.4220x; 2.4220x over previous
//
#include <hip/hip_runtime.h>

#define NN 200000
#define NB 64
#define NWG (NN / NB)   // 3125

typedef unsigned short u16;
typedef unsigned int u32;
typedef __attribute__((ext_vector_type(8))) short short8;
typedef __attribute__((ext_vector_type(4))) float f32x4;

__device__ __forceinline__ u16 f2bf(float x) {
  u32 u = __float_as_uint(x);
  u += 0x7FFFu + ((u >> 16) & 1u);
  return (u16)(u >> 16);
}
__device__ __forceinline__ float sigf(float x) {
  float e = __builtin_amdgcn_exp2f(x * -1.44269504f);
  return __builtin_amdgcn_rcpf(1.0f + e);
}
__device__ __forceinline__ float tanhf_(float x) {
  float e = __builtin_amdgcn_exp2f(x * 2.88539008f);
  return 1.0f - 2.0f * __builtin_amdgcn_rcpf(1.0f + e);
}

// msg[n][k] = bf16(feat[n][k] / out_norm[n]); 16 threads per row, 8 elems each
__global__ void k_prep_msg(const float* __restrict__ feat, const float* __restrict__ onorm,
                           u16* __restrict__ msg) {
  int i = blockIdx.x * 256 + threadIdx.x;   // 3,200,000 total, exact
  int row = i >> 4, c8 = (i & 15) * 8;
  const float4 a = *(const float4*)(feat + (size_t)row * 128 + c8);
  const float4 b = *(const float4*)(feat + (size_t)row * 128 + c8 + 4);
  float s = 1.0f / onorm[row];
  short8 v = { (short)f2bf(a.x * s), (short)f2bf(a.y * s), (short)f2bf(a.z * s), (short)f2bf(a.w * s),
               (short)f2bf(b.x * s), (short)f2bf(b.y * s), (short)f2bf(b.z * s), (short)f2bf(b.w * s) };
  *(short8*)(msg + (size_t)row * 128 + c8) = v;
}

__global__ void k_prep_w(const float* __restrict__ Wih, const float* __restrict__ Whh,
                         const float* __restrict__ Wlin, const float* __restrict__ bih,
                         const float* __restrict__ bhh, u16* __restrict__ wihb,
                         u16* __restrict__ whhb, u16* __restrict__ wlinb,
                         float* __restrict__ bsum) {
  int i = blockIdx.x * 256 + threadIdx.x;   // 147,968 total, exact
  if (i < 65536) wihb[i] = f2bf(Wih[i]);
  else if (i < 131072) whhb[i - 65536] = f2bf(Whh[i - 65536]);
  else if (i < 147456) wlinb[i - 131072] = f2bf(Wlin[i - 131072]);
  else { int j = i - 147456; bsum[j] = bih[j] + bhh[j]; }
}

__global__ void k_hist(const int* __restrict__ degs, int* __restrict__ hist, int n) {
  __shared__ int lh[33];
  if (threadIdx.x < 33) lh[threadIdx.x] = 0;
  __syncthreads();
  int i = blockIdx.x * 256 + threadIdx.x;
  if (i < n) atomicAdd(&lh[degs[i]], 1);
  __syncthreads();
  if (threadIdx.x < 33 && lh[threadIdx.x]) atomicAdd(&hist[threadIdx.x], lh[threadIdx.x]);
}

// descending-degree exclusive prefix (longest blocks scheduled first)
__global__ void k_scan(const int* __restrict__ hist, int* __restrict__ basep) {
  if (threadIdx.x == 0 && blockIdx.x == 0) {
    int a = 0;
    for (int d = 32; d >= 1; --d) { basep[d] = a; a += hist[d]; }
    basep[0] = a;
  }
}

// block-aggregated scatter: one global atomic per (block, degree) instead of per node
__global__ void k_scatter(const int* __restrict__ degs, int* __restrict__ basep,
                          int* __restrict__ perm, int n) {
  __shared__ int lh[33], lbase[33], lc[33];
  int t = threadIdx.x;
  if (t < 33) { lh[t] = 0; lc[t] = 0; }
  __syncthreads();
  int i = blockIdx.x * 256 + t;
  int d = (i < n) ? degs[i] : 0;
  if (i < n) atomicAdd(&lh[d], 1);
  __syncthreads();
  if (t < 33 && lh[t]) lbase[t] = atomicAdd(&basep[t], lh[t]);
  __syncthreads();
  if (i < n) { int r = atomicAdd(&lc[d], 1); perm[lbase[d] + r] = i; }
}

// (512,4): cap 128 VGPR/wave (fits — R1/R2 compiled to exactly 128),
// admits 2 co-resident 512-thread blocks per CU. (512,8) forced a 64-reg
// budget and spilled the whole working set -> 10x regression in R3.
__global__ __launch_bounds__(512, 4) void k_main(
    const u16* __restrict__ msg, const u16* __restrict__ wihb,
    const u16* __restrict__ whhb, const u16* __restrict__ wlinb,
    const float* __restrict__ bsum, const float* __restrict__ blin,
    const float* __restrict__ inorm, const int* __restrict__ nbrs,
    const int* __restrict__ degs, const int* __restrict__ perm,
    float* __restrict__ out) {
  __shared__ alignas(16) u16 Xl[64 * 136];   // 17408 B
  __shared__ alignas(16) u16 Hl[64 * 136];   // 17408 B
  __shared__ int gidl[64];
  // total ~35.3 KB -> 2 blocks/CU alongside the VGPR limit

  const int tid = threadIdx.x;
  const int w = tid >> 6;
  const int lane = tid & 63;
  const int l15 = lane & 15;
  const int g4 = lane >> 4;
  const int w16 = w * 16;
  const int gr = tid >> 4;         // gather rows gr and gr+32
  const int gc = (tid & 15) * 8;
  const int base = blockIdx.x * NB;

  if (tid < NB) gidl[tid] = perm[base + tid];
  // zero Hl (64*136 u16 = 4352 u32)
  {
    u32* hz = (u32*)Hl;
#pragma unroll
    for (int s = 0; s < 8; ++s) hz[tid + s * 512] = 0;
    if (tid < 256) hz[tid + 4096] = 0;
  }
  __syncthreads();

  const int gid0 = gidl[gr], gid1 = gidl[gr + 32];

  // per-wave B fragments (row-major W rows are exactly the B-frag layout)
  short8 fih[4][4], fhh[4][4];
#pragma unroll
  for (int g = 0; g < 4; ++g)
#pragma unroll
    for (int kk = 0; kk < 4; ++kk) {
      size_t o = (size_t)(g * 128 + w16 + l15) * 128 + kk * 32 + g4 * 8;
      fih[g][kk] = *(const short8*)(wihb + o);
      fhh[g][kk] = *(const short8*)(whhb + o);
    }
  float bias[4];
#pragma unroll
  for (int g = 0; g < 4; ++g) bias[g] = bsum[g * 128 + w16 + l15];

  // packed per-cell degrees (u8 x4 per row-frag)
  u32 dgp[4];
#pragma unroll
  for (int r = 0; r < 4; ++r) {
    u32 p = 0;
#pragma unroll
    for (int q = 0; q < 4; ++q) p |= ((u32)degs[gidl[r * 16 + g4 * 4 + q]]) << (8 * q);
    dgp[r] = p;
  }
  const int maxdeg = degs[gidl[0]];   // sorted descending -> first is WG max

  // 2-deep prefetch pipeline: nbrn = index for step t+1, pf = data for step t
  int nbrn0 = nbrs[(size_t)gid0 * 32];
  int nbrn1 = nbrs[(size_t)gid1 * 32];
  short8 pf0 = *(const short8*)(msg + (size_t)nbrn0 * 128 + gc);
  short8 pf1 = *(const short8*)(msg + (size_t)nbrn1 * 128 + gc);
  if (maxdeg > 1) {
    nbrn0 = nbrs[(size_t)gid0 * 32 + 1];
    nbrn1 = nbrs[(size_t)gid1 * 32 + 1];
  }

  float c[4][4] = {};
  u16 hbf[4][4] = {};

  for (int t = 0; t < maxdeg; ++t) {
    // commit X(t) and h(t-1)
    *(short8*)(&Xl[gr * 136 + gc]) = pf0;
    *(short8*)(&Xl[(gr + 32) * 136 + gc]) = pf1;
    if (t > 0) {
#pragma unroll
      for (int rr = 0; rr < 4; ++rr)
#pragma unroll
        for (int q = 0; q < 4; ++q)
          Hl[(rr * 16 + g4 * 4 + q) * 136 + w16 + l15] = hbf[rr][q];
    }
    __syncthreads();   // barrier A: tiles ready

    if (t + 1 < maxdeg) {   // gather msg(t+1) with index loaded last step
      pf0 = *(const short8*)(msg + (size_t)nbrn0 * 128 + gc);
      pf1 = *(const short8*)(msg + (size_t)nbrn1 * 128 + gc);
    }
    if (t + 2 < maxdeg) {   // load neighbor index for step t+2
      nbrn0 = nbrs[(size_t)gid0 * 32 + t + 2];
      nbrn1 = nbrs[(size_t)gid1 * 32 + t + 2];
    }

    // two passes over row-fragments: acc stays at 32 regs; pass0's TRANS
    // epilogue overlaps pass1's MFMAs
#pragma unroll
    for (int rp = 0; rp < 2; ++rp) {
      f32x4 acc[2][4];
#pragma unroll
      for (int r = 0; r < 2; ++r)
#pragma unroll
        for (int g = 0; g < 4; ++g) acc[r][g] = (f32x4){bias[g], bias[g], bias[g], bias[g]};
#pragma unroll
      for (int kk = 0; kk < 4; ++kk) {
        short8 ax0 = *(const short8*)(&Xl[(rp * 32 + l15) * 136 + kk * 32 + g4 * 8]);
        short8 ax1 = *(const short8*)(&Xl[(rp * 32 + 16 + l15) * 136 + kk * 32 + g4 * 8]);
        short8 ah0 = *(const short8*)(&Hl[(rp * 32 + l15) * 136 + kk * 32 + g4 * 8]);
        short8 ah1 = *(const short8*)(&Hl[(rp * 32 + 16 + l15) * 136 + kk * 32 + g4 * 8]);
#pragma unroll
        for (int g = 0; g < 4; ++g) {
          acc[0][g] = __builtin_amdgcn_mfma_f32_16x16x32_bf16(ax0, fih[g][kk], acc[0][g], 0, 0, 0);
          acc[0][g] = __builtin_amdgcn_mfma_f32_16x16x32_bf16(ah0, fhh[g][kk], acc[0][g], 0, 0, 0);
          acc[1][g] = __builtin_amdgcn_mfma_f32_16x16x32_bf16(ax1, fih[g][kk], acc[1][g], 0, 0, 0);
          acc[1][g] = __builtin_amdgcn_mfma_f32_16x16x32_bf16(ah1, fhh[g][kk], acc[1][g], 0, 0, 0);
        }
      }
      // epilogue: LSTM cell (fp32 state, masked by t < deg)
#pragma unroll
      for (int r = 0; r < 2; ++r) {
        const int rr = rp * 2 + r;
#pragma unroll
        for (int q = 0; q < 4; ++q) {
          float iv = sigf(acc[r][0][q]);
          float fv = sigf(acc[r][1][q]);
          float gv = tanhf_(acc[r][2][q]);
          float ov = sigf(acc[r][3][q]);
          float cn = fv * c[rr][q] + iv * gv;
          float hn = ov * tanhf_(cn);
          bool act = (int)((dgp[rr] >> (8 * q)) & 255u) > t;
          c[rr][q] = act ? cn : c[rr][q];
          hbf[rr][q] = act ? f2bf(hn) : hbf[rr][q];
        }
      }
    }
    __syncthreads();   // barrier B: all reads done before next commit
  }

  // final h commit
#pragma unroll
  for (int rr = 0; rr < 4; ++rr)
#pragma unroll
    for (int q = 0; q < 4; ++q)
      Hl[(rr * 16 + g4 * 4 + q) * 136 + w16 + l15] = hbf[rr][q];
  __syncthreads();

  // out = (h @ W_lin^T) / in_norm + b_lin   (wave w owns out cols 16w..16w+15)
  short8 wl[4];
#pragma unroll
  for (int kk = 0; kk < 4; ++kk)
    wl[kk] = *(const short8*)(wlinb + (size_t)(w16 + l15) * 128 + kk * 32 + g4 * 8);
  f32x4 a2[4] = {};
#pragma unroll
  for (int kk = 0; kk < 4; ++kk)
#pragma unroll
    for (int r = 0; r < 4; ++r) {
      short8 ah = *(const short8*)(&Hl[(r * 16 + l15) * 136 + kk * 32 + g4 * 8]);
      a2[r] = __builtin_amdgcn_mfma_f32_16x16x32_bf16(ah, wl[kk], a2[r], 0, 0, 0);
    }
  float blv = blin[w16 + l15];
#pragma unroll
  for (int r = 0; r < 4; ++r)
#pragma unroll
    for (int q = 0; q < 4; ++q) {
      int nl = r * 16 + g4 * 4 + q;
      int g = gidl[nl];
      out[(size_t)g * 128 + w16 + l15] = a2[r][q] / inorm[g] + blv;
    }
}

extern "C" void kernel_launch(void* const* d_in, const int* in_sizes, int n_in,
                              void* d_out, int out_size, void* d_ws, size_t ws_size,
                              hipStream_t stream) {
  const float* feat    = (const float*)d_in[0];
  const float* in_norm = (const float*)d_in[1];
  const float* out_nrm = (const float*)d_in[2];
  const float* W_ih    = (const float*)d_in[3];
  const float* W_hh    = (const float*)d_in[4];
  const float* b_ih    = (const float*)d_in[5];
  const float* b_hh    = (const float*)d_in[6];
  const float* W_lin   = (const float*)d_in[7];
  const float* b_lin   = (const float*)d_in[8];
  const int* neighbors = (const int*)d_in[9];
  const int* degrees   = (const int*)d_in[10];
  float* out = (float*)d_out;

  char* ws = (char*)d_ws;
  u16* msg    = (u16*)(ws);                 // 51,200,000 B
  u16* wihb   = (u16*)(ws + 51200000);      //    131,072 B
  u16* whhb   = (u16*)(ws + 51331072);      //    131,072 B
  u16* wlinb  = (u16*)(ws + 51462144);      //     32,768 B
  float* bsum = (float*)(ws + 51494912);    //      2,048 B
  int* perm   = (int*)(ws + 51496960);      //    800,000 B
  int* hist   = (int*)(ws + 52296960);      // 64 ints
  int* basep  = hist + 64;                  // 33 ints
  if (ws_size < 52297600) return;           // need ~52.3 MB scratch

  hipMemsetAsync(hist, 0, 64 * 4, stream);
  k_prep_msg<<<12500, 256, 0, stream>>>(feat, out_nrm, msg);
  k_prep_w<<<578, 256, 0, stream>>>(W_ih, W_hh, W_lin, b_ih, b_hh, wihb, whhb, wlinb, bsum);
  k_hist<<<782, 256, 0, stream>>>(degrees, hist, NN);
  k_scan<<<1, 1, 0, stream>>>(hist, basep);
  k_scatter<<<782, 256, 0, stream>>>(degrees, basep, perm, NN);
  k_main<<<NWG, 512, 0, stream>>>(msg, wihb, whhb, wlinb, bsum, b_lin, in_norm,
                                  neighbors, degrees, perm, out);
}

// Round 5
// 2074.135 us; speedup vs baseline: 6.1812x; 2.5521x over previous
//
#include <hip/hip_runtime.h>

#define NN 200000
#define NB 64
#define NWG (NN / NB)   // 3125

typedef unsigned short u16;
typedef unsigned int u32;
typedef __attribute__((ext_vector_type(8))) short short8;
typedef __attribute__((ext_vector_type(4))) float f32x4;

#define LOG2E 1.4426950408889634f
#define TWOLOG2E 2.8853900817779268f

__device__ __forceinline__ u16 f2bf(float x) {
  u32 u = __float_as_uint(x);
  u += 0x7FFFu + ((u >> 16) & 1u);
  return (u16)(u >> 16);
}

// msg[n][k] = bf16(feat[n][k] / out_norm[n]); 16 threads per row, 8 elems each
__global__ void k_prep_msg(const float* __restrict__ feat, const float* __restrict__ onorm,
                           u16* __restrict__ msg) {
  int i = blockIdx.x * 256 + threadIdx.x;   // 3,200,000 total, exact
  int row = i >> 4, c8 = (i & 15) * 8;
  const float4 a = *(const float4*)(feat + (size_t)row * 128 + c8);
  const float4 b = *(const float4*)(feat + (size_t)row * 128 + c8 + 4);
  float s = 1.0f / onorm[row];
  short8 v = { (short)f2bf(a.x * s), (short)f2bf(a.y * s), (short)f2bf(a.z * s), (short)f2bf(a.w * s),
               (short)f2bf(b.x * s), (short)f2bf(b.y * s), (short)f2bf(b.z * s), (short)f2bf(b.w * s) };
  *(short8*)(msg + (size_t)row * 128 + c8) = v;
}

// Weights with the gate nonlinearity scale FOLDED IN:
//  gates i,f,o (rows 0..127, 128..255, 384..511): x * -log2(e)  (sigmoid via exp2)
//  gate  g     (rows 256..383):                   x * 2*log2(e) (tanh via exp2)
__global__ void k_prep_w(const float* __restrict__ Wih, const float* __restrict__ Whh,
                         const float* __restrict__ Wlin, const float* __restrict__ bih,
                         const float* __restrict__ bhh, u16* __restrict__ wihb,
                         u16* __restrict__ whhb, u16* __restrict__ wlinb,
                         float* __restrict__ bsum) {
  int i = blockIdx.x * 256 + threadIdx.x;   // 147,968 total, exact
  if (i < 65536) {
    int gate = (i >> 7) >> 7;
    float s = (gate == 2) ? TWOLOG2E : -LOG2E;
    wihb[i] = f2bf(Wih[i] * s);
  } else if (i < 131072) {
    int j = i - 65536;
    int gate = (j >> 7) >> 7;
    float s = (gate == 2) ? TWOLOG2E : -LOG2E;
    whhb[j] = f2bf(Whh[j] * s);
  } else if (i < 147456) {
    wlinb[i - 131072] = f2bf(Wlin[i - 131072]);
  } else {
    int j = i - 147456;   // 0..511
    float s = ((j >> 7) == 2) ? TWOLOG2E : -LOG2E;
    bsum[j] = (bih[j] + bhh[j]) * s;
  }
}

__global__ void k_hist(const int* __restrict__ degs, int* __restrict__ hist, int n) {
  __shared__ int lh[33];
  if (threadIdx.x < 33) lh[threadIdx.x] = 0;
  __syncthreads();
  int i = blockIdx.x * 256 + threadIdx.x;
  if (i < n) atomicAdd(&lh[degs[i]], 1);
  __syncthreads();
  if (threadIdx.x < 33 && lh[threadIdx.x]) atomicAdd(&hist[threadIdx.x], lh[threadIdx.x]);
}

__global__ void k_scan(const int* __restrict__ hist, int* __restrict__ basep) {
  if (threadIdx.x == 0 && blockIdx.x == 0) {
    int a = 0;
    for (int d = 32; d >= 1; --d) { basep[d] = a; a += hist[d]; }
    basep[0] = a;
  }
}

__global__ void k_scatter(const int* __restrict__ degs, int* __restrict__ basep,
                          int* __restrict__ perm, int n) {
  __shared__ int lh[33], lbase[33], lc[33];
  int t = threadIdx.x;
  if (t < 33) { lh[t] = 0; lc[t] = 0; }
  __syncthreads();
  int i = blockIdx.x * 256 + t;
  int d = (i < n) ? degs[i] : 0;
  if (i < n) atomicAdd(&lh[d], 1);
  __syncthreads();
  if (t < 33 && lh[t]) lbase[t] = atomicAdd(&basep[t], lh[t]);
  __syncthreads();
  if (i < n) { int r = atomicAdd(&lc[d], 1); perm[lbase[d] + r] = i; }
}

// (512,2): 256-reg total budget (VGPR+AGPR unified) — proven spill-free in R2.
// 8-wave blocks are structurally forced (512 W-rows @ 16 cols/wave = 128 weight
// regs/wave); 1 block/CU. So: minimize the post-barrier critical path instead.
__global__ __launch_bounds__(512, 2) void k_main(
    const u16* __restrict__ msg, const u16* __restrict__ wihb,
    const u16* __restrict__ whhb, const u16* __restrict__ wlinb,
    const float* __restrict__ bsum, const float* __restrict__ blin,
    const float* __restrict__ inorm, const int* __restrict__ nbrs,
    const int* __restrict__ degs, const int* __restrict__ perm,
    float* __restrict__ out) {
  __shared__ alignas(16) u16 Xl[2][64 * 136];   // 2 x 17408 B
  __shared__ alignas(16) u16 Hl[2][64 * 136];   // 2 x 17408 B
  __shared__ int gidl[64];

  const int tid = threadIdx.x;
  const int w = tid >> 6;
  const int lane = tid & 63;
  const int l15 = lane & 15;
  const int g4 = lane >> 4;
  const int w16 = w * 16;
  const int gr = tid >> 4;         // gather rows gr and gr+32
  const int gc = (tid & 15) * 8;
  const int base = blockIdx.x * NB;

  if (tid < NB) gidl[tid] = perm[base + tid];
  // zero Hl[0] (Hl[1] is fully written at t=0 before first read)
  {
    u32* hz = (u32*)Hl[0];
#pragma unroll
    for (int s = 0; s < 8; ++s) hz[tid + s * 512] = 0;
    if (tid < 256) hz[tid + 4096] = 0;
  }
  __syncthreads();

  const int gid0 = gidl[gr], gid1 = gidl[gr + 32];

  // per-wave B fragments (row-major W rows are exactly the B-frag layout)
  short8 fih[4][4], fhh[4][4];
#pragma unroll
  for (int g = 0; g < 4; ++g)
#pragma unroll
    for (int kk = 0; kk < 4; ++kk) {
      size_t o = (size_t)(g * 128 + w16 + l15) * 128 + kk * 32 + g4 * 8;
      fih[g][kk] = *(const short8*)(wihb + o);
      fhh[g][kk] = *(const short8*)(whhb + o);
    }
  float bias[4];
#pragma unroll
  for (int g = 0; g < 4; ++g) bias[g] = bsum[g * 128 + w16 + l15];

  u32 dgp[4];
#pragma unroll
  for (int r = 0; r < 4; ++r) {
    u32 p = 0;
#pragma unroll
    for (int q = 0; q < 4; ++q) p |= ((u32)degs[gidl[r * 16 + g4 * 4 + q]]) << (8 * q);
    dgp[r] = p;
  }
  const int maxdeg = degs[gidl[0]];   // sorted descending -> first is WG max

  // X(0): gather and commit into Xl[0]
  {
    int i0 = nbrs[(size_t)gid0 * 32], i1 = nbrs[(size_t)gid1 * 32];
    short8 p0 = *(const short8*)(msg + (size_t)i0 * 128 + gc);
    short8 p1 = *(const short8*)(msg + (size_t)i1 * 128 + gc);
    *(short8*)(&Xl[0][gr * 136 + gc]) = p0;
    *(short8*)(&Xl[0][(gr + 32) * 136 + gc]) = p1;
  }
  float c[4][4] = {};
  u16 hbf[4][4] = {};
  __syncthreads();

  // Xacc = bias + X(0) @ W_ih^T  (the h-independent half of the gates)
  f32x4 Xacc[4][4];
#pragma unroll
  for (int r = 0; r < 4; ++r)
#pragma unroll
    for (int g = 0; g < 4; ++g) Xacc[r][g] = (f32x4){bias[g], bias[g], bias[g], bias[g]};
#pragma unroll
  for (int kk = 0; kk < 4; ++kk) {
    short8 a0 = *(const short8*)(&Xl[0][(l15) * 136 + kk * 32 + g4 * 8]);
    short8 a1 = *(const short8*)(&Xl[0][(16 + l15) * 136 + kk * 32 + g4 * 8]);
    short8 a2 = *(const short8*)(&Xl[0][(32 + l15) * 136 + kk * 32 + g4 * 8]);
    short8 a3 = *(const short8*)(&Xl[0][(48 + l15) * 136 + kk * 32 + g4 * 8]);
#pragma unroll
    for (int g = 0; g < 4; ++g) {
      Xacc[0][g] = __builtin_amdgcn_mfma_f32_16x16x32_bf16(a0, fih[g][kk], Xacc[0][g], 0, 0, 0);
      Xacc[1][g] = __builtin_amdgcn_mfma_f32_16x16x32_bf16(a1, fih[g][kk], Xacc[1][g], 0, 0, 0);
      Xacc[2][g] = __builtin_amdgcn_mfma_f32_16x16x32_bf16(a2, fih[g][kk], Xacc[2][g], 0, 0, 0);
      Xacc[3][g] = __builtin_amdgcn_mfma_f32_16x16x32_bf16(a3, fih[g][kk], Xacc[3][g], 0, 0, 0);
    }
  }

  // gather X(1)
  short8 pf0, pf1;
  if (maxdeg > 1) {
    int i0 = nbrs[(size_t)gid0 * 32 + 1], i1 = nbrs[(size_t)gid1 * 32 + 1];
    pf0 = *(const short8*)(msg + (size_t)i0 * 128 + gc);
    pf1 = *(const short8*)(msg + (size_t)i1 * 128 + gc);
  }

  int cur = 0;
  for (int t = 0; t < maxdeg; ++t) {
    const int nxt = cur ^ 1;
    // issue next-next neighbor index load early (consumed in phase D)
    int ni0 = 0, ni1 = 0;
    if (t + 2 < maxdeg) {
      ni0 = nbrs[(size_t)gid0 * 32 + t + 2];
      ni1 = nbrs[(size_t)gid1 * 32 + t + 2];
    }

    // A: h-dependent half — ds_read Hl[cur], 64 hh-MFMAs into Xacc
    {
      const u16* Hc = &Hl[cur][0];
#pragma unroll
      for (int kk = 0; kk < 4; ++kk) {
        short8 a0 = *(const short8*)(&Hc[(l15) * 136 + kk * 32 + g4 * 8]);
        short8 a1 = *(const short8*)(&Hc[(16 + l15) * 136 + kk * 32 + g4 * 8]);
        short8 a2 = *(const short8*)(&Hc[(32 + l15) * 136 + kk * 32 + g4 * 8]);
        short8 a3 = *(const short8*)(&Hc[(48 + l15) * 136 + kk * 32 + g4 * 8]);
#pragma unroll
        for (int g = 0; g < 4; ++g) {
          Xacc[0][g] = __builtin_amdgcn_mfma_f32_16x16x32_bf16(a0, fhh[g][kk], Xacc[0][g], 0, 0, 0);
          Xacc[1][g] = __builtin_amdgcn_mfma_f32_16x16x32_bf16(a1, fhh[g][kk], Xacc[1][g], 0, 0, 0);
          Xacc[2][g] = __builtin_amdgcn_mfma_f32_16x16x32_bf16(a2, fhh[g][kk], Xacc[2][g], 0, 0, 0);
          Xacc[3][g] = __builtin_amdgcn_mfma_f32_16x16x32_bf16(a3, fhh[g][kk], Xacc[3][g], 0, 0, 0);
        }
      }
    }

    // B: epilogue. Preacts are pre-scaled: i,f,o by -log2e, g by 2log2e.
    //    sig(x)  = rcp(1+exp2(x'));  tanh(x) = (exp2(x')-1)/(exp2(x')+1)
    //    i*g and o*tanh(c) share one rcp via the product denominator.
#pragma unroll
    for (int r = 0; r < 4; ++r)
#pragma unroll
      for (int q = 0; q < 4; ++q) {
        float ei = __builtin_amdgcn_exp2f(Xacc[r][0][q]);
        float ef = __builtin_amdgcn_exp2f(Xacc[r][1][q]);
        float eg = __builtin_amdgcn_exp2f(Xacc[r][2][q]);
        float eo = __builtin_amdgcn_exp2f(Xacc[r][3][q]);
        float fv  = __builtin_amdgcn_rcpf(1.0f + ef);
        float rig = __builtin_amdgcn_rcpf((1.0f + ei) * (1.0f + eg));
        float ig  = (eg - 1.0f) * rig;
        float cn  = fv * c[r][q] + ig;
        float ec  = __builtin_amdgcn_exp2f(cn * TWOLOG2E);
        float rho = __builtin_amdgcn_rcpf((1.0f + eo) * (1.0f + ec));
        float hn  = (ec - 1.0f) * rho;
        bool act = (int)((dgp[r] >> (8 * q)) & 255u) > t;
        c[r][q] = act ? cn : c[r][q];
        hbf[r][q] = act ? f2bf(hn) : hbf[r][q];
      }

    // C: commit X(t+1) and h(t) into the alternate buffers
    if (t + 1 < maxdeg) {
      *(short8*)(&Xl[nxt][gr * 136 + gc]) = pf0;
      *(short8*)(&Xl[nxt][(gr + 32) * 136 + gc]) = pf1;
    }
#pragma unroll
    for (int r = 0; r < 4; ++r)
#pragma unroll
      for (int q = 0; q < 4; ++q)
        Hl[nxt][(r * 16 + g4 * 4 + q) * 136 + w16 + l15] = hbf[r][q];

    // D: gather X(t+2) with the index issued at the top of this iteration
    if (t + 2 < maxdeg) {
      pf0 = *(const short8*)(msg + (size_t)ni0 * 128 + gc);
      pf1 = *(const short8*)(msg + (size_t)ni1 * 128 + gc);
    }

    __syncthreads();   // single barrier: Hl[nxt]/Xl[nxt] complete for all waves

    // F: h-independent half for step t+1 (fills the pipe; off the h-chain)
    if (t + 1 < maxdeg) {
      const u16* Xc = &Xl[nxt][0];
#pragma unroll
      for (int r = 0; r < 4; ++r)
#pragma unroll
        for (int g = 0; g < 4; ++g) Xacc[r][g] = (f32x4){bias[g], bias[g], bias[g], bias[g]};
#pragma unroll
      for (int kk = 0; kk < 4; ++kk) {
        short8 a0 = *(const short8*)(&Xc[(l15) * 136 + kk * 32 + g4 * 8]);
        short8 a1 = *(const short8*)(&Xc[(16 + l15) * 136 + kk * 32 + g4 * 8]);
        short8 a2 = *(const short8*)(&Xc[(32 + l15) * 136 + kk * 32 + g4 * 8]);
        short8 a3 = *(const short8*)(&Xc[(48 + l15) * 136 + kk * 32 + g4 * 8]);
#pragma unroll
        for (int g = 0; g < 4; ++g) {
          Xacc[0][g] = __builtin_amdgcn_mfma_f32_16x16x32_bf16(a0, fih[g][kk], Xacc[0][g], 0, 0, 0);
          Xacc[1][g] = __builtin_amdgcn_mfma_f32_16x16x32_bf16(a1, fih[g][kk], Xacc[1][g], 0, 0, 0);
          Xacc[2][g] = __builtin_amdgcn_mfma_f32_16x16x32_bf16(a2, fih[g][kk], Xacc[2][g], 0, 0, 0);
          Xacc[3][g] = __builtin_amdgcn_mfma_f32_16x16x32_bf16(a3, fih[g][kk], Xacc[3][g], 0, 0, 0);
        }
      }
    }
    cur = nxt;
  }

  // final h is in Hl[cur]
  const u16* Hf = &Hl[cur][0];

  // out = (h @ W_lin^T) / in_norm + b_lin   (wave w owns out cols 16w..16w+15)
  short8 wl[4];
#pragma unroll
  for (int kk = 0; kk < 4; ++kk)
    wl[kk] = *(const short8*)(wlinb + (size_t)(w16 + l15) * 128 + kk * 32 + g4 * 8);
  f32x4 a2[4] = {};
#pragma unroll
  for (int kk = 0; kk < 4; ++kk)
#pragma unroll
    for (int r = 0; r < 4; ++r) {
      short8 ah = *(const short8*)(&Hf[(r * 16 + l15) * 136 + kk * 32 + g4 * 8]);
      a2[r] = __builtin_amdgcn_mfma_f32_16x16x32_bf16(ah, wl[kk], a2[r], 0, 0, 0);
    }
  float blv = blin[w16 + l15];
#pragma unroll
  for (int r = 0; r < 4; ++r)
#pragma unroll
    for (int q = 0; q < 4; ++q) {
      int nl = r * 16 + g4 * 4 + q;
      int g = gidl[nl];
      out[(size_t)g * 128 + w16 + l15] = a2[r][q] / inorm[g] + blv;
    }
}

extern "C" void kernel_launch(void* const* d_in, const int* in_sizes, int n_in,
                              void* d_out, int out_size, void* d_ws, size_t ws_size,
                              hipStream_t stream) {
  const float* feat    = (const float*)d_in[0];
  const float* in_norm = (const float*)d_in[1];
  const float* out_nrm = (const float*)d_in[2];
  const float* W_ih    = (const float*)d_in[3];
  const float* W_hh    = (const float*)d_in[4];
  const float* b_ih    = (const float*)d_in[5];
  const float* b_hh    = (const float*)d_in[6];
  const float* W_lin   = (const float*)d_in[7];
  const float* b_lin   = (const float*)d_in[8];
  const int* neighbors = (const int*)d_in[9];
  const int* degrees   = (const int*)d_in[10];
  float* out = (float*)d_out;

  char* ws = (char*)d_ws;
  u16* msg    = (u16*)(ws);                 // 51,200,000 B
  u16* wihb   = (u16*)(ws + 51200000);      //    131,072 B
  u16* whhb   = (u16*)(ws + 51331072);      //    131,072 B
  u16* wlinb  = (u16*)(ws + 51462144);      //     32,768 B
  float* bsum = (float*)(ws + 51494912);    //      2,048 B
  int* perm   = (int*)(ws + 51496960);      //    800,000 B
  int* hist   = (int*)(ws + 52296960);      // 64 ints
  int* basep  = hist + 64;                  // 33 ints
  if (ws_size < 52297600) return;           // need ~52.3 MB scratch

  hipMemsetAsync(hist, 0, 64 * 4, stream);
  k_prep_msg<<<12500, 256, 0, stream>>>(feat, out_nrm, msg);
  k_prep_w<<<578, 256, 0, stream>>>(W_ih, W_hh, W_lin, b_ih, b_hh, wihb, whhb, wlinb, bsum);
  k_hist<<<782, 256, 0, stream>>>(degrees, hist, NN);
  k_scan<<<1, 1, 0, stream>>>(hist, basep);
  k_scatter<<<782, 256, 0, stream>>>(degrees, basep, perm, NN);
  k_main<<<NWG, 512, 0, stream>>>(msg, wihb, whhb, wlinb, bsum, b_lin, in_norm,
                                  neighbors, degrees, perm, out);
}

// Round 6
// 1069.683 us; speedup vs baseline: 11.9855x; 1.9390x over previous
//
#include <hip/hip_runtime.h>

#define NN 200000
#define NB 64
#define NWG (NN / NB)   // 3125

typedef unsigned short u16;
typedef unsigned int u32;
typedef __attribute__((ext_vector_type(8))) short short8;
typedef __attribute__((ext_vector_type(4))) float f32x4;

#define LOG2E 1.4426950408889634f
#define TWOLOG2E 2.8853900817779268f

__device__ __forceinline__ u16 f2bf(float x) {
  u32 u = __float_as_uint(x);
  u += 0x7FFFu + ((u >> 16) & 1u);
  return (u16)(u >> 16);
}

// msg[n][k] = bf16(feat[n][k] / out_norm[n]); 16 threads per row, 8 elems each
__global__ void k_prep_msg(const float* __restrict__ feat, const float* __restrict__ onorm,
                           u16* __restrict__ msg) {
  int i = blockIdx.x * 256 + threadIdx.x;   // 3,200,000 total, exact
  int row = i >> 4, c8 = (i & 15) * 8;
  const float4 a = *(const float4*)(feat + (size_t)row * 128 + c8);
  const float4 b = *(const float4*)(feat + (size_t)row * 128 + c8 + 4);
  float s = 1.0f / onorm[row];
  short8 v = { (short)f2bf(a.x * s), (short)f2bf(a.y * s), (short)f2bf(a.z * s), (short)f2bf(a.w * s),
               (short)f2bf(b.x * s), (short)f2bf(b.y * s), (short)f2bf(b.z * s), (short)f2bf(b.w * s) };
  *(short8*)(msg + (size_t)row * 128 + c8) = v;
}

// Weights with the gate nonlinearity scale FOLDED IN:
//  gates i,f,o (rows 0..127, 128..255, 384..511): x * -log2(e)  (sigmoid via exp2)
//  gate  g     (rows 256..383):                   x * 2*log2(e) (tanh via exp2)
__global__ void k_prep_w(const float* __restrict__ Wih, const float* __restrict__ Whh,
                         const float* __restrict__ Wlin, const float* __restrict__ bih,
                         const float* __restrict__ bhh, u16* __restrict__ wihb,
                         u16* __restrict__ whhb, u16* __restrict__ wlinb,
                         float* __restrict__ bsum) {
  int i = blockIdx.x * 256 + threadIdx.x;   // 147,968 total, exact
  if (i < 65536) {
    int gate = i >> 14;
    float s = (gate == 2) ? TWOLOG2E : -LOG2E;
    wihb[i] = f2bf(Wih[i] * s);
  } else if (i < 131072) {
    int j = i - 65536;
    int gate = j >> 14;
    float s = (gate == 2) ? TWOLOG2E : -LOG2E;
    whhb[j] = f2bf(Whh[j] * s);
  } else if (i < 147456) {
    wlinb[i - 131072] = f2bf(Wlin[i - 131072]);
  } else {
    int j = i - 147456;   // 0..511
    float s = ((j >> 7) == 2) ? TWOLOG2E : -LOG2E;
    bsum[j] = (bih[j] + bhh[j]) * s;
  }
}

__global__ void k_hist(const int* __restrict__ degs, int* __restrict__ hist, int n) {
  __shared__ int lh[33];
  if (threadIdx.x < 33) lh[threadIdx.x] = 0;
  __syncthreads();
  int i = blockIdx.x * 256 + threadIdx.x;
  if (i < n) atomicAdd(&lh[degs[i]], 1);
  __syncthreads();
  if (threadIdx.x < 33 && lh[threadIdx.x]) atomicAdd(&hist[threadIdx.x], lh[threadIdx.x]);
}

__global__ void k_scan(const int* __restrict__ hist, int* __restrict__ basep) {
  if (threadIdx.x == 0 && blockIdx.x == 0) {
    int a = 0;
    for (int d = 32; d >= 1; --d) { basep[d] = a; a += hist[d]; }
    basep[0] = a;
  }
}

__global__ void k_scatter(const int* __restrict__ degs, int* __restrict__ basep,
                          int* __restrict__ perm, int n) {
  __shared__ int lh[33], lbase[33], lc[33];
  int t = threadIdx.x;
  if (t < 33) { lh[t] = 0; lc[t] = 0; }
  __syncthreads();
  int i = blockIdx.x * 256 + t;
  int d = (i < n) ? degs[i] : 0;
  if (i < n) atomicAdd(&lh[d], 1);
  __syncthreads();
  if (t < 33 && lh[t]) lbase[t] = atomicAdd(&basep[t], lh[t]);
  __syncthreads();
  if (i < n) { int r = atomicAdd(&lc[d], 1); perm[lbase[d] + r] = i; }
}

// (512,2): 256-reg budget. R2's envelope (weights 128 + acc 32 two-pass +
// state ~60) is the proven no-spill configuration; everything added here is
// register-neutral. 1 block/CU is structural (weights-in-regs).
__global__ __launch_bounds__(512, 2) void k_main(
    const u16* __restrict__ msg, const u16* __restrict__ wihb,
    const u16* __restrict__ whhb, const u16* __restrict__ wlinb,
    const float* __restrict__ bsum, const float* __restrict__ blin,
    const float* __restrict__ inorm, const int* __restrict__ nbrs,
    const int* __restrict__ degs, const int* __restrict__ perm,
    float* __restrict__ out) {
  __shared__ alignas(16) u16 Xl[2][64 * 136];   // double-buffered, 2x17408 B
  __shared__ alignas(16) u16 Hl[2][64 * 136];
  __shared__ int gidl[64];

  const int tid = threadIdx.x;
  const int w = tid >> 6;
  const int lane = tid & 63;
  const int l15 = lane & 15;
  const int g4 = lane >> 4;
  const int w16 = w * 16;
  const int gr = tid >> 4;         // gather rows gr and gr+32
  const int gc = (tid & 15) * 8;
  const int base = blockIdx.x * NB;

  if (tid < NB) gidl[tid] = perm[base + tid];
  // zero Hl[0] (Hl[1] fully written before first read)
  {
    u32* hz = (u32*)Hl[0];
#pragma unroll
    for (int s = 0; s < 8; ++s) hz[tid + s * 512] = 0;
    if (tid < 256) hz[tid + 4096] = 0;
  }
  __syncthreads();

  const int gid0 = gidl[gr], gid1 = gidl[gr + 32];
  const int* nb0 = nbrs + (size_t)gid0 * 32;
  const int* nb1 = nbrs + (size_t)gid1 * 32;

  // per-wave B fragments (row-major W rows are exactly the B-frag layout)
  short8 fih[4][4], fhh[4][4];
#pragma unroll
  for (int g = 0; g < 4; ++g)
#pragma unroll
    for (int kk = 0; kk < 4; ++kk) {
      size_t o = (size_t)(g * 128 + w16 + l15) * 128 + kk * 32 + g4 * 8;
      fih[g][kk] = *(const short8*)(wihb + o);
      fhh[g][kk] = *(const short8*)(whhb + o);
    }
  float bias[4];
#pragma unroll
  for (int g = 0; g < 4; ++g) bias[g] = bsum[g * 128 + w16 + l15];

  u32 dgp[4];
#pragma unroll
  for (int r = 0; r < 4; ++r) {
    u32 p = 0;
#pragma unroll
    for (int q = 0; q < 4; ++q) p |= ((u32)degs[gidl[r * 16 + g4 * 4 + q]]) << (8 * q);
    dgp[r] = p;
  }
  const int maxdeg = degs[gidl[0]];   // sorted descending -> first is WG max

  // prologue: X(0) gathered and committed; ni = neighbor index for step 1
  {
    int i0 = nb0[0], i1 = nb1[0];
    short8 p0 = *(const short8*)(msg + (size_t)i0 * 128 + gc);
    short8 p1 = *(const short8*)(msg + (size_t)i1 * 128 + gc);
    *(short8*)(&Xl[0][gr * 136 + gc]) = p0;
    *(short8*)(&Xl[0][(gr + 32) * 136 + gc]) = p1;
  }
  int ni0 = 0, ni1 = 0;
  if (maxdeg > 1) { ni0 = nb0[1]; ni1 = nb1[1]; }

  float c[4][4] = {};
  u16 hbf[4][4] = {};
  __syncthreads();

  int cur = 0;
  for (int t = 0; t < maxdeg; ++t) {
    const int nxt = cur ^ 1;
    // gather X(t+1) with the index loaded last iteration; load index for t+2.
    // Latency of both hides under the two MFMA+epilogue passes below.
    short8 pf0, pf1;
    if (t + 1 < maxdeg) {
      pf0 = *(const short8*)(msg + (size_t)ni0 * 128 + gc);
      pf1 = *(const short8*)(msg + (size_t)ni1 * 128 + gc);
    }
    if (t + 2 < maxdeg) { ni0 = nb0[t + 2]; ni1 = nb1[t + 2]; }

    const u16* Xc = &Xl[cur][0];
    const u16* Hc = &Hl[cur][0];

    // two row-passes; per pass: X phase then H phase (no back-to-back
    // dependent MFMA pairs — 4-instruction reuse distance per accumulator)
#pragma unroll
    for (int rp = 0; rp < 2; ++rp) {
      f32x4 acc[2][4];
#pragma unroll
      for (int r = 0; r < 2; ++r)
#pragma unroll
        for (int g = 0; g < 4; ++g) acc[r][g] = (f32x4){bias[g], bias[g], bias[g], bias[g]};

#pragma unroll
      for (int rf = 0; rf < 2; ++rf) {
        short8 ax[4];
#pragma unroll
        for (int kk = 0; kk < 4; ++kk)
          ax[kk] = *(const short8*)(&Xc[(rp * 32 + rf * 16 + l15) * 136 + kk * 32 + g4 * 8]);
#pragma unroll
        for (int kk = 0; kk < 4; ++kk)
#pragma unroll
          for (int g = 0; g < 4; ++g)
            acc[rf][g] = __builtin_amdgcn_mfma_f32_16x16x32_bf16(ax[kk], fih[g][kk], acc[rf][g], 0, 0, 0);
      }
#pragma unroll
      for (int rf = 0; rf < 2; ++rf) {
        short8 ah[4];
#pragma unroll
        for (int kk = 0; kk < 4; ++kk)
          ah[kk] = *(const short8*)(&Hc[(rp * 32 + rf * 16 + l15) * 136 + kk * 32 + g4 * 8]);
#pragma unroll
        for (int kk = 0; kk < 4; ++kk)
#pragma unroll
          for (int g = 0; g < 4; ++g)
            acc[rf][g] = __builtin_amdgcn_mfma_f32_16x16x32_bf16(ah[kk], fhh[g][kk], acc[rf][g], 0, 0, 0);
      }

      // epilogue: preacts pre-scaled (i,f,o by -log2e; g by 2log2e)
      //  sig(x)=rcp(1+exp2(x')); tanh(x)=(exp2(x')-1)*rcp(exp2(x')+1)
      //  i*g and o*tanh(c) each share one rcp via product denominators
#pragma unroll
      for (int r = 0; r < 2; ++r) {
        const int rr = rp * 2 + r;
#pragma unroll
        for (int q = 0; q < 4; ++q) {
          float ei = __builtin_amdgcn_exp2f(acc[r][0][q]);
          float ef = __builtin_amdgcn_exp2f(acc[r][1][q]);
          float eg = __builtin_amdgcn_exp2f(acc[r][2][q]);
          float eo = __builtin_amdgcn_exp2f(acc[r][3][q]);
          float fv  = __builtin_amdgcn_rcpf(1.0f + ef);
          float rig = __builtin_amdgcn_rcpf((1.0f + ei) * (1.0f + eg));
          float ig  = (eg - 1.0f) * rig;
          float cn  = fv * c[rr][q] + ig;
          float ec  = __builtin_amdgcn_exp2f(cn * TWOLOG2E);
          float rho = __builtin_amdgcn_rcpf((1.0f + eo) * (1.0f + ec));
          float hn  = (ec - 1.0f) * rho;
          bool act = (int)((dgp[rr] >> (8 * q)) & 255u) > t;
          c[rr][q] = act ? cn : c[rr][q];
          hbf[rr][q] = act ? f2bf(hn) : hbf[rr][q];
        }
      }
    }

    // commit X(t+1) and h(t) into the alternate buffers; ONE barrier/step
    // (safe: writes to [nxt] only touch the buffer no wave reads this step)
    if (t + 1 < maxdeg) {
      *(short8*)(&Xl[nxt][gr * 136 + gc]) = pf0;
      *(short8*)(&Xl[nxt][(gr + 32) * 136 + gc]) = pf1;
    }
#pragma unroll
    for (int rr = 0; rr < 4; ++rr)
#pragma unroll
      for (int q = 0; q < 4; ++q)
        Hl[nxt][(rr * 16 + g4 * 4 + q) * 136 + w16 + l15] = hbf[rr][q];
    __syncthreads();
    cur = nxt;
  }

  // final h is in Hl[cur]
  const u16* Hf = &Hl[cur][0];

  // out = (h @ W_lin^T) / in_norm + b_lin   (wave w owns out cols 16w..16w+15)
  short8 wl[4];
#pragma unroll
  for (int kk = 0; kk < 4; ++kk)
    wl[kk] = *(const short8*)(wlinb + (size_t)(w16 + l15) * 128 + kk * 32 + g4 * 8);
  f32x4 a2[4] = {};
#pragma unroll
  for (int kk = 0; kk < 4; ++kk)
#pragma unroll
    for (int r = 0; r < 4; ++r) {
      short8 ah = *(const short8*)(&Hf[(r * 16 + l15) * 136 + kk * 32 + g4 * 8]);
      a2[r] = __builtin_amdgcn_mfma_f32_16x16x32_bf16(ah, wl[kk], a2[r], 0, 0, 0);
    }
  float blv = blin[w16 + l15];
#pragma unroll
  for (int r = 0; r < 4; ++r)
#pragma unroll
    for (int q = 0; q < 4; ++q) {
      int nl = r * 16 + g4 * 4 + q;
      int g = gidl[nl];
      out[(size_t)g * 128 + w16 + l15] = a2[r][q] / inorm[g] + blv;
    }
}

extern "C" void kernel_launch(void* const* d_in, const int* in_sizes, int n_in,
                              void* d_out, int out_size, void* d_ws, size_t ws_size,
                              hipStream_t stream) {
  const float* feat    = (const float*)d_in[0];
  const float* in_norm = (const float*)d_in[1];
  const float* out_nrm = (const float*)d_in[2];
  const float* W_ih    = (const float*)d_in[3];
  const float* W_hh    = (const float*)d_in[4];
  const float* b_ih    = (const float*)d_in[5];
  const float* b_hh    = (const float*)d_in[6];
  const float* W_lin   = (const float*)d_in[7];
  const float* b_lin   = (const float*)d_in[8];
  const int* neighbors = (const int*)d_in[9];
  const int* degrees   = (const int*)d_in[10];
  float* out = (float*)d_out;

  char* ws = (char*)d_ws;
  u16* msg    = (u16*)(ws);                 // 51,200,000 B
  u16* wihb   = (u16*)(ws + 51200000);      //    131,072 B
  u16* whhb   = (u16*)(ws + 51331072);      //    131,072 B
  u16* wlinb  = (u16*)(ws + 51462144);      //     32,768 B
  float* bsum = (float*)(ws + 51494912);    //      2,048 B
  int* perm   = (int*)(ws + 51496960);      //    800,000 B
  int* hist   = (int*)(ws + 52296960);      // 64 ints
  int* basep  = hist + 64;                  // 33 ints
  if (ws_size < 52297600) return;           // need ~52.3 MB scratch

  hipMemsetAsync(hist, 0, 64 * 4, stream);
  k_prep_msg<<<12500, 256, 0, stream>>>(feat, out_nrm, msg);
  k_prep_w<<<578, 256, 0, stream>>>(W_ih, W_hh, W_lin, b_ih, b_hh, wihb, whhb, wlinb, bsum);
  k_hist<<<782, 256, 0, stream>>>(degrees, hist, NN);
  k_scan<<<1, 1, 0, stream>>>(hist, basep);
  k_scatter<<<782, 256, 0, stream>>>(degrees, basep, perm, NN);
  k_main<<<NWG, 512, 0, stream>>>(msg, wihb, whhb, wlinb, bsum, b_lin, in_norm,
                                  neighbors, degrees, perm, out);
}